// Round 1
// baseline (136.436 us; speedup 1.0000x reference)
//
#include <hip/hip_runtime.h>

// ---------------------------------------------------------------------------
// MLP-GNN fused op for MI355X (gfx950).
//   v  = tanh(tanh(z @ cw1^T + cb1) @ cw2^T + cb2)                    [N,128]
//   vn = tanh(tanh([z|z_] @ nw1^T + nb1) @ nw2^T + nb2).sum(axis=K)   [N,128]
//   dc = [v | vn] @ ow^T + ob                                         [N,64]
// Strategy: bf16 MFMA (16x16x32), f32 accum. 3 kernels:
//   cur_kernel:  v  -> feat[:, 0:128]   (bf16, in d_ws)
//   nbr_kernel:  vn -> feat[:, 128:256] (dominant: reads z_ = 327.7 MB)
//   out_kernel:  dc -> d_out (f32)
// ---------------------------------------------------------------------------

typedef __bf16 bf16;
typedef __bf16 bf16x2 __attribute__((ext_vector_type(2)));
typedef __bf16 bf16x8 __attribute__((ext_vector_type(8)));
typedef float  f32x4  __attribute__((ext_vector_type(4)));

#define MFMA(a, b, c) __builtin_amdgcn_mfma_f32_16x16x32_bf16((a), (b), (c), 0, 0, 0)

// tanh(x) = sign(x) * (1 - 2/(e^{2|x|}+1)); exp2-based, inf-safe (inf -> 1).
__device__ __forceinline__ float fast_tanh(float x) {
    float ax = __builtin_fabsf(x);
    float t  = __builtin_amdgcn_exp2f(ax * 2.885390081777927f); // 2*log2(e)
    float r  = 1.0f - 2.0f * __builtin_amdgcn_rcpf(t + 1.0f);
    return __builtin_copysignf(r, x);
}

__device__ __forceinline__ bf16x8 cvt8(f32x4 a, f32x4 b) {
    bf16x8 r;
    r[0] = (bf16)a[0]; r[1] = (bf16)a[1]; r[2] = (bf16)a[2]; r[3] = (bf16)a[3];
    r[4] = (bf16)b[0]; r[5] = (bf16)b[1]; r[6] = (bf16)b[2]; r[7] = (bf16)b[3];
    return r;
}

// LDS tiles with 128-bf16 rows (256 B = 16 x 16B chunks), chunk-XOR swizzle so
// ds_read_b128 A/B-frag reads (16 rows x same chunk) are bank-spread.
__device__ __forceinline__ int swz128(int row, int col) {
    int c = (col >> 3) ^ (row & 15);
    return row * 256 + c * 16 + (col & 7) * 2;
}
// 256-bf16 rows (512 B = 32 chunks)
__device__ __forceinline__ int swz256(int row, int col) {
    int c = (col >> 3) ^ (row & 15);
    return row * 512 + c * 16 + (col & 7) * 2;
}

__device__ __forceinline__ void st_pair(char* base, int off, float a, float b) {
    bf16x2 p = {(bf16)a, (bf16)b};
    *(bf16x2*)(base + off) = p;
}

// ---------------------------------------------------------------------------
// Kernel B: neighbor branch. One n per block-iteration: 32 rows of
// zc=[z(n)|z_(n,k)] -> MLP(256->128->128) -> sum over k -> feat[n][128:256].
// Weights resident in VGPR fragments. Layer1 operand-swapped (D = W1 * zc^T)
// so h1 D-frags pack as b32 pairs into LDS; layer2 normal orientation so the
// neighbor-sum is a per-lane add + 2x shfl_xor.
// ---------------------------------------------------------------------------
__global__ __launch_bounds__(256, 2) void nbr_kernel(
    const float* __restrict__ z, const float* __restrict__ zn,
    const float* __restrict__ w1, const float* __restrict__ b1,
    const float* __restrict__ w2, const float* __restrict__ b2,
    bf16* __restrict__ feat, int N)
{
    __shared__ char zc_lds[32 * 256];  // z_ half of concat (cols 128..255), swizzled
    __shared__ char h1_lds[32 * 256];  // layer-1 activations, swizzled
    __shared__ char zr_lds[256];       // z row (cols 0..127), linear (broadcast reads)

    const int t     = threadIdx.x;
    const int wv    = t >> 6;
    const int lane  = t & 63;
    const int g     = lane >> 4;
    const int li    = lane & 15;
    const int hbase = wv * 32;   // this wave's 32-wide h slice

    // ---- persistent weight fragments (once per block) ----
    bf16x8 w1f[2][8];  // A-frags for swapped L1: W1[hbase+16ht+li][kb*32+8g .. +8]
#pragma unroll
    for (int ht = 0; ht < 2; ++ht)
#pragma unroll
        for (int kb = 0; kb < 8; ++kb) {
            const float* p = w1 + (size_t)(hbase + 16*ht + li) * 256 + kb*32 + 8*g;
            w1f[ht][kb] = cvt8(*(const f32x4*)p, *(const f32x4*)(p + 4));
        }
    bf16x8 w2f[2][4];  // B-frags for L2: W2[hbase+16nt+li][kb*32+8g .. +8]
#pragma unroll
    for (int nt = 0; nt < 2; ++nt)
#pragma unroll
        for (int kb = 0; kb < 4; ++kb) {
            const float* p = w2 + (size_t)(hbase + 16*nt + li) * 128 + kb*32 + 8*g;
            w2f[nt][kb] = cvt8(*(const f32x4*)p, *(const f32x4*)(p + 4));
        }
    float b1v[2][4];
#pragma unroll
    for (int ht = 0; ht < 2; ++ht)
#pragma unroll
        for (int r = 0; r < 4; ++r) b1v[ht][r] = b1[hbase + 16*ht + 4*g + r];
    float b2v[2];
#pragma unroll
    for (int nt = 0; nt < 2; ++nt) b2v[nt] = b2[hbase + 16*nt + li];

    const int sm = t >> 3;        // staging row 0..31
    const int sc = (t & 7) * 16;  // staging col

    const int stride = gridDim.x;

    // ---- prologue: load first n into registers (T14 async-stage) ----
    f32x4 r0, r1, r2, r3, rz0, rz1;
    {
        int n = blockIdx.x;
        const float* src = zn + ((size_t)n * 32 + sm) * 128 + sc;
        r0 = *(const f32x4*)(src);
        r1 = *(const f32x4*)(src + 4);
        r2 = *(const f32x4*)(src + 8);
        r3 = *(const f32x4*)(src + 12);
        if (t < 16) {
            const float* sz = z + (size_t)n * 128 + t * 8;
            rz0 = *(const f32x4*)sz;
            rz1 = *(const f32x4*)(sz + 4);
        }
    }

    const f32x4 vzero = {0.f, 0.f, 0.f, 0.f};

    for (int n = blockIdx.x; n < N; n += stride) {
        // ---- write staged registers into LDS ----
        *(bf16x8*)(zc_lds + swz128(sm, sc))     = cvt8(r0, r1);
        *(bf16x8*)(zc_lds + swz128(sm, sc + 8)) = cvt8(r2, r3);
        if (t < 16) *(bf16x8*)(zr_lds + t * 16) = cvt8(rz0, rz1);
        __syncthreads();

        // ---- issue next-n loads; latency hides under the MFMAs below ----
        {
            int nn = n + stride;
            if (nn < N) {
                const float* src = zn + ((size_t)nn * 32 + sm) * 128 + sc;
                r0 = *(const f32x4*)(src);
                r1 = *(const f32x4*)(src + 4);
                r2 = *(const f32x4*)(src + 8);
                r3 = *(const f32x4*)(src + 12);
                if (t < 16) {
                    const float* sz = z + (size_t)nn * 128 + t * 8;
                    rz0 = *(const f32x4*)sz;
                    rz1 = *(const f32x4*)(sz + 4);
                }
            }
        }

        // ---- layer 1 (swapped: D[h][m] = sum_d W1[h][d] * zc[m][d]) ----
        bf16x8 az[4];
#pragma unroll
        for (int kb = 0; kb < 4; ++kb)
            az[kb] = *(const bf16x8*)(zr_lds + kb * 64 + g * 16);  // z half: m-independent

        f32x4 acc1[2][2];
#pragma unroll
        for (int a = 0; a < 2; ++a)
#pragma unroll
            for (int b = 0; b < 2; ++b) acc1[a][b] = vzero;

#pragma unroll
        for (int kb = 0; kb < 4; ++kb)
#pragma unroll
            for (int ht = 0; ht < 2; ++ht)
#pragma unroll
                for (int mt = 0; mt < 2; ++mt)
                    acc1[ht][mt] = MFMA(w1f[ht][kb], az[kb], acc1[ht][mt]);
#pragma unroll
        for (int kb = 4; kb < 8; ++kb) {
            bf16x8 bz[2];
#pragma unroll
            for (int mt = 0; mt < 2; ++mt)
                bz[mt] = *(const bf16x8*)(zc_lds + swz128(16*mt + li, (kb - 4)*32 + 8*g));
#pragma unroll
            for (int ht = 0; ht < 2; ++ht)
#pragma unroll
                for (int mt = 0; mt < 2; ++mt)
                    acc1[ht][mt] = MFMA(w1f[ht][kb], bz[mt], acc1[ht][mt]);
        }

        // finish L1: tanh + pack pairs -> h1_lds[m][h]
#pragma unroll
        for (int ht = 0; ht < 2; ++ht)
#pragma unroll
            for (int mt = 0; mt < 2; ++mt) {
                float v0 = fast_tanh(acc1[ht][mt][0] + b1v[ht][0]);
                float v1 = fast_tanh(acc1[ht][mt][1] + b1v[ht][1]);
                float v2 = fast_tanh(acc1[ht][mt][2] + b1v[ht][2]);
                float v3 = fast_tanh(acc1[ht][mt][3] + b1v[ht][3]);
                int m = 16*mt + li;
                int h = hbase + 16*ht + 4*g;
                st_pair(h1_lds, swz128(m, h),     v0, v1);
                st_pair(h1_lds, swz128(m, h + 2), v2, v3);
            }
        __syncthreads();

        // ---- layer 2 (normal: D[m][h_out]) ----
        f32x4 acc2[2][2];
#pragma unroll
        for (int a = 0; a < 2; ++a)
#pragma unroll
            for (int b = 0; b < 2; ++b) acc2[a][b] = vzero;

#pragma unroll
        for (int kb = 0; kb < 4; ++kb) {
            bf16x8 ah[2];
#pragma unroll
            for (int mt = 0; mt < 2; ++mt)
                ah[mt] = *(const bf16x8*)(h1_lds + swz128(16*mt + li, kb*32 + 8*g));
#pragma unroll
            for (int mt = 0; mt < 2; ++mt)
#pragma unroll
                for (int nt = 0; nt < 2; ++nt)
                    acc2[mt][nt] = MFMA(ah[mt], w2f[nt][kb], acc2[mt][nt]);
        }

        // finish L2: tanh, then sum over the 32 neighbor rows
        float s0 = 0.f, s1 = 0.f;
#pragma unroll
        for (int mt = 0; mt < 2; ++mt)
#pragma unroll
            for (int r = 0; r < 4; ++r) {
                s0 += fast_tanh(acc2[mt][0][r] + b2v[0]);
                s1 += fast_tanh(acc2[mt][1][r] + b2v[1]);
            }
        s0 += __shfl_xor(s0, 16); s0 += __shfl_xor(s0, 32);
        s1 += __shfl_xor(s1, 16); s1 += __shfl_xor(s1, 32);
        if (lane < 16) {
            bf16* dst = feat + (size_t)n * 256 + 128 + hbase + lane;
            dst[0]  = (bf16)s0;
            dst[16] = (bf16)s1;
        }
        // NOTE: no trailing barrier needed — the top-of-loop barrier orders
        // next-iteration LDS writes against this iteration's reads.
        __syncthreads();
    }
}

// ---------------------------------------------------------------------------
// Kernel A: cur branch, 64 rows of z per block -> feat[n][0:128] (bf16).
// Both layers operand-swapped; direct packed b32 global stores (L2 merges).
// ---------------------------------------------------------------------------
__global__ __launch_bounds__(256, 2) void cur_kernel(
    const float* __restrict__ z,
    const float* __restrict__ w1, const float* __restrict__ b1,
    const float* __restrict__ w2, const float* __restrict__ b2,
    bf16* __restrict__ feat, int N)
{
    __shared__ char z_lds[64 * 256];
    __shared__ char h1_lds[64 * 256];

    const int t = threadIdx.x;
    const int wv = t >> 6, lane = t & 63, g = lane >> 4, li = lane & 15;
    const int hbase = wv * 32;
    const int n0 = blockIdx.x * 64;

    bf16x8 w1f[2][4], w2f[2][4];
#pragma unroll
    for (int ht = 0; ht < 2; ++ht)
#pragma unroll
        for (int kb = 0; kb < 4; ++kb) {
            const float* p1 = w1 + (size_t)(hbase + 16*ht + li) * 128 + kb*32 + 8*g;
            w1f[ht][kb] = cvt8(*(const f32x4*)p1, *(const f32x4*)(p1 + 4));
            const float* p2 = w2 + (size_t)(hbase + 16*ht + li) * 128 + kb*32 + 8*g;
            w2f[ht][kb] = cvt8(*(const f32x4*)p2, *(const f32x4*)(p2 + 4));
        }
    float b1v[2][4], b2v[2][4];
#pragma unroll
    for (int ht = 0; ht < 2; ++ht)
#pragma unroll
        for (int r = 0; r < 4; ++r) {
            b1v[ht][r] = b1[hbase + 16*ht + 4*g + r];
            b2v[ht][r] = b2[hbase + 16*ht + 4*g + r];
        }

    // stage 64 z rows (clamped for the tail block)
    {
        int m = t >> 2;
        int c0 = (t & 3) * 32;
        int row = n0 + m; if (row > N - 1) row = N - 1;
        const float* src = z + (size_t)row * 128 + c0;
#pragma unroll
        for (int q = 0; q < 4; ++q) {
            f32x4 a = *(const f32x4*)(src + 8*q);
            f32x4 b = *(const f32x4*)(src + 8*q + 4);
            *(bf16x8*)(z_lds + swz128(m, c0 + 8*q)) = cvt8(a, b);
        }
    }
    __syncthreads();

    const f32x4 vzero = {0.f, 0.f, 0.f, 0.f};
    f32x4 acc1[2][4];
#pragma unroll
    for (int a = 0; a < 2; ++a)
#pragma unroll
        for (int b = 0; b < 4; ++b) acc1[a][b] = vzero;

#pragma unroll
    for (int kb = 0; kb < 4; ++kb) {
        bf16x8 bz[4];
#pragma unroll
        for (int mt = 0; mt < 4; ++mt)
            bz[mt] = *(const bf16x8*)(z_lds + swz128(16*mt + li, kb*32 + 8*g));
#pragma unroll
        for (int ht = 0; ht < 2; ++ht)
#pragma unroll
            for (int mt = 0; mt < 4; ++mt)
                acc1[ht][mt] = MFMA(w1f[ht][kb], bz[mt], acc1[ht][mt]);
    }
#pragma unroll
    for (int ht = 0; ht < 2; ++ht)
#pragma unroll
        for (int mt = 0; mt < 4; ++mt) {
            float v0 = fast_tanh(acc1[ht][mt][0] + b1v[ht][0]);
            float v1 = fast_tanh(acc1[ht][mt][1] + b1v[ht][1]);
            float v2 = fast_tanh(acc1[ht][mt][2] + b1v[ht][2]);
            float v3 = fast_tanh(acc1[ht][mt][3] + b1v[ht][3]);
            int m = 16*mt + li;
            int h = hbase + 16*ht + 4*g;
            st_pair(h1_lds, swz128(m, h),     v0, v1);
            st_pair(h1_lds, swz128(m, h + 2), v2, v3);
        }
    __syncthreads();

    f32x4 acc2[2][4];
#pragma unroll
    for (int a = 0; a < 2; ++a)
#pragma unroll
        for (int b = 0; b < 4; ++b) acc2[a][b] = vzero;

#pragma unroll
    for (int kb = 0; kb < 4; ++kb) {
        bf16x8 bh[4];
#pragma unroll
        for (int mt = 0; mt < 4; ++mt)
            bh[mt] = *(const bf16x8*)(h1_lds + swz128(16*mt + li, kb*32 + 8*g));
#pragma unroll
        for (int ht = 0; ht < 2; ++ht)
#pragma unroll
            for (int mt = 0; mt < 4; ++mt)
                acc2[ht][mt] = MFMA(w2f[ht][kb], bh[mt], acc2[ht][mt]);
    }
#pragma unroll
    for (int ht = 0; ht < 2; ++ht)
#pragma unroll
        for (int mt = 0; mt < 4; ++mt) {
            float v0 = fast_tanh(acc2[ht][mt][0] + b2v[ht][0]);
            float v1 = fast_tanh(acc2[ht][mt][1] + b2v[ht][1]);
            float v2 = fast_tanh(acc2[ht][mt][2] + b2v[ht][2]);
            float v3 = fast_tanh(acc2[ht][mt][3] + b2v[ht][3]);
            int row = n0 + 16*mt + li;
            if (row < N) {
                int h = hbase + 16*ht + 4*g;
                bf16* dst = feat + (size_t)row * 256 + h;
                bf16x2 p01 = {(bf16)v0, (bf16)v1};
                bf16x2 p23 = {(bf16)v2, (bf16)v3};
                *(bf16x2*)(dst)     = p01;
                *(bf16x2*)(dst + 2) = p23;
            }
        }
}

// ---------------------------------------------------------------------------
// Kernel C: dc = feat[N,256] @ ow^T + ob -> f32 out. 64 rows/block.
// ---------------------------------------------------------------------------
__global__ __launch_bounds__(256, 2) void out_kernel(
    const bf16* __restrict__ feat,
    const float* __restrict__ ow, const float* __restrict__ ob,
    float* __restrict__ out, int N)
{
    __shared__ char f_lds[64 * 512];

    const int t = threadIdx.x, wv = t >> 6, lane = t & 63, g = lane >> 4, li = lane & 15;
    const int cbase = wv * 16;     // wave's 16 output columns
    const int n0 = blockIdx.x * 64;

    bf16x8 owf[8];
#pragma unroll
    for (int kb = 0; kb < 8; ++kb) {
        const float* p = ow + (size_t)(cbase + li) * 256 + kb*32 + 8*g;
        owf[kb] = cvt8(*(const f32x4*)p, *(const f32x4*)(p + 4));
    }
    float obv = ob[cbase + li];

    {
        int m = t >> 2;
        int c0 = (t & 3) * 64;
        int row = n0 + m; if (row > N - 1) row = N - 1;   // clamp: no ws overrun
        const bf16* src = feat + (size_t)row * 256 + c0;
#pragma unroll
        for (int q = 0; q < 8; ++q)
            *(bf16x8*)(f_lds + swz256(m, c0 + 8*q)) = *(const bf16x8*)(src + 8*q);
    }
    __syncthreads();

    const f32x4 vzero = {0.f, 0.f, 0.f, 0.f};
    f32x4 acc[4];
#pragma unroll
    for (int a = 0; a < 4; ++a) acc[a] = vzero;

#pragma unroll
    for (int kb = 0; kb < 8; ++kb) {
        bf16x8 af[4];
#pragma unroll
        for (int mt = 0; mt < 4; ++mt)
            af[mt] = *(const bf16x8*)(f_lds + swz256(16*mt + li, kb*32 + 8*g));
#pragma unroll
        for (int mt = 0; mt < 4; ++mt)
            acc[mt] = MFMA(af[mt], owf[kb], acc[mt]);
    }
#pragma unroll
    for (int mt = 0; mt < 4; ++mt)
#pragma unroll
        for (int r = 0; r < 4; ++r) {
            int row = n0 + 16*mt + 4*g + r;
            if (row < N) out[(size_t)row * 64 + cbase + li] = acc[mt][r] + obv;
        }
}

// ---------------------------------------------------------------------------
extern "C" void kernel_launch(void* const* d_in, const int* in_sizes, int n_in,
                              void* d_out, int out_size, void* d_ws, size_t ws_size,
                              hipStream_t stream) {
    const float* z   = (const float*)d_in[0];
    const float* zn  = (const float*)d_in[1];
    const float* cw1 = (const float*)d_in[2];
    const float* cb1 = (const float*)d_in[3];
    const float* cw2 = (const float*)d_in[4];
    const float* cb2 = (const float*)d_in[5];
    const float* nw1 = (const float*)d_in[6];
    const float* nb1 = (const float*)d_in[7];
    const float* nw2 = (const float*)d_in[8];
    const float* nb2 = (const float*)d_in[9];
    const float* ow  = (const float*)d_in[10];
    const float* ob  = (const float*)d_in[11];
    float* out = (float*)d_out;
    bf16* feat = (bf16*)d_ws;                 // [N][256] bf16 = 10.24 MB

    const int N = in_sizes[0] / 128;          // 20000
    const int nblk = (N + 63) / 64;           // 313

    (void)n_in; (void)out_size; (void)ws_size;

    cur_kernel<<<nblk, 256, 0, stream>>>(z, cw1, cb1, cw2, cb2, feat, N);
    nbr_kernel<<<512, 256, 0, stream>>>(z, zn, nw1, nb1, nw2, nb2, feat, N);
    out_kernel<<<nblk, 256, 0, stream>>>(feat, ow, ob, out, N);
}

// Round 2
// 126.301 us; speedup vs baseline: 1.0802x; 1.0802x over previous
//
#include <hip/hip_runtime.h>

// ---------------------------------------------------------------------------
// MLP-GNN fused op for MI355X (gfx950).
//   v  = tanh(tanh(z @ cw1^T + cb1) @ cw2^T + cb2)                    [N,128]
//   vn = tanh(tanh([z|z_] @ nw1^T + nb1) @ nw2^T + nb2).sum(axis=K)   [N,128]
//   dc = [v | vn] @ ow^T + ob                                         [N,64]
// bf16 MFMA (16x16x32), f32 accum. 3 kernels:
//   cur_kernel:  v -> feat[:,0:128]  AND  u1[n][h] = z@nw1[:,:128]^T + nb1
//                (the z-half of the neighbor concat is n-constant -> hoisted)
//   nbr_kernel:  vn -> feat[:,128:256]; 2 n's per iteration, 2 barriers/pair
//   out_kernel:  dc -> d_out (f32)
// ---------------------------------------------------------------------------

typedef __bf16 bf16;
typedef __bf16 bf16x2 __attribute__((ext_vector_type(2)));
typedef __bf16 bf16x8 __attribute__((ext_vector_type(8)));
typedef float  f32x4  __attribute__((ext_vector_type(4)));

#define MFMA(a, b, c) __builtin_amdgcn_mfma_f32_16x16x32_bf16((a), (b), (c), 0, 0, 0)

// tanh(x) = sign(x) * (1 - 2/(e^{2|x|}+1)); exp2-based, inf-safe (inf -> 1).
__device__ __forceinline__ float fast_tanh(float x) {
    float ax = __builtin_fabsf(x);
    float t  = __builtin_amdgcn_exp2f(ax * 2.885390081777927f); // 2*log2(e)
    float r  = 1.0f - 2.0f * __builtin_amdgcn_rcpf(t + 1.0f);
    return __builtin_copysignf(r, x);
}

__device__ __forceinline__ bf16x8 cvt8(f32x4 a, f32x4 b) {
    bf16x8 r;
    r[0] = (bf16)a[0]; r[1] = (bf16)a[1]; r[2] = (bf16)a[2]; r[3] = (bf16)a[3];
    r[4] = (bf16)b[0]; r[5] = (bf16)b[1]; r[6] = (bf16)b[2]; r[7] = (bf16)b[3];
    return r;
}

// LDS tiles with 128-bf16 rows (256 B = 16 x 16B chunks), chunk-XOR swizzle so
// ds_read_b128 frag reads (16 rows x same chunk) are bank-spread.
__device__ __forceinline__ int swz128(int row, int col) {
    int c = (col >> 3) ^ (row & 15);
    return row * 256 + c * 16 + (col & 7) * 2;
}
// 256-bf16 rows (512 B = 32 chunks)
__device__ __forceinline__ int swz256(int row, int col) {
    int c = (col >> 3) ^ (row & 15);
    return row * 512 + c * 16 + (col & 7) * 2;
}

__device__ __forceinline__ void st_pair(char* base, int off, float a, float b) {
    bf16x2 p = {(bf16)a, (bf16)b};
    *(bf16x2*)(base + off) = p;
}

// ---------------------------------------------------------------------------
// Kernel B: neighbor branch. One PAIR (n0=2p, n1=2p+1) per iteration; 32 rows
// of z_ each. L1 is operand-swapped (D[h][m]) over the z_-half only; the
// z-half contribution arrives as the precomputed per-row bias u1[n][h].
// 2 barriers per pair. Weights + staging + u1 prefetch all register-resident.
// ---------------------------------------------------------------------------
__global__ __launch_bounds__(256, 2) void nbr_kernel(
    const float* __restrict__ zn, const float* __restrict__ u1,
    const float* __restrict__ w1, const float* __restrict__ w2,
    const float* __restrict__ b2,
    bf16* __restrict__ feat, int NP)
{
    __shared__ char zc_lds[2][32 * 256];
    __shared__ char h1_lds[2][32 * 256];

    const int t = threadIdx.x;
    const int wv = t >> 6, lane = t & 63, g = lane >> 4, li = lane & 15;
    const int hbase = wv * 32;

    // z_-half of W1 (cols 128..255) as swapped-L1 A-frags
    bf16x8 w1f[2][4];
#pragma unroll
    for (int ht = 0; ht < 2; ++ht)
#pragma unroll
        for (int kb = 0; kb < 4; ++kb) {
            const float* p = w1 + (size_t)(hbase + 16*ht + li) * 256 + 128 + kb*32 + 8*g;
            w1f[ht][kb] = cvt8(*(const f32x4*)p, *(const f32x4*)(p + 4));
        }
    bf16x8 w2f[2][4];
#pragma unroll
    for (int nt = 0; nt < 2; ++nt)
#pragma unroll
        for (int kb = 0; kb < 4; ++kb) {
            const float* p = w2 + (size_t)(hbase + 16*nt + li) * 128 + kb*32 + 8*g;
            w2f[nt][kb] = cvt8(*(const f32x4*)p, *(const f32x4*)(p + 4));
        }
    float b2v[2];
#pragma unroll
    for (int nt = 0; nt < 2; ++nt) b2v[nt] = b2[hbase + 16*nt + li];

    const int sm  = t >> 3;        // staging row 0..31
    const int scf = (t & 7) * 16;  // staging col (floats)
    const int stride = gridDim.x;

    f32x4 r[2][4];   // staged z_ rows for the pair
    f32x4 uu[2][2];  // u1 bias for the pair
    {
        int p = blockIdx.x;
#pragma unroll
        for (int j = 0; j < 2; ++j) {
            const float* src = zn + ((size_t)(2*p + j) * 32 + sm) * 128 + scf;
#pragma unroll
            for (int q = 0; q < 4; ++q) r[j][q] = *(const f32x4*)(src + 4*q);
#pragma unroll
            for (int ht = 0; ht < 2; ++ht)
                uu[j][ht] = *(const f32x4*)(u1 + (size_t)(2*p + j) * 128 + hbase + 16*ht + 4*g);
        }
    }

    const f32x4 vzero = {0.f, 0.f, 0.f, 0.f};

    for (int p = blockIdx.x; p < NP; p += stride) {
        // ---- write staged pair into LDS ----
#pragma unroll
        for (int j = 0; j < 2; ++j) {
            *(bf16x8*)(zc_lds[j] + swz128(sm, scf))     = cvt8(r[j][0], r[j][1]);
            *(bf16x8*)(zc_lds[j] + swz128(sm, scf + 8)) = cvt8(r[j][2], r[j][3]);
        }
        __syncthreads();   // B1

        // ---- prefetch next pair's z_ (consumed at next loop top) ----
        const int pp = p + stride;
        if (pp < NP) {
#pragma unroll
            for (int j = 0; j < 2; ++j) {
                const float* src = zn + ((size_t)(2*pp + j) * 32 + sm) * 128 + scf;
#pragma unroll
                for (int q = 0; q < 4; ++q) r[j][q] = *(const f32x4*)(src + 4*q);
            }
        }

        // ---- layer 1 (swapped, z_-half only): 32 MFMAs, 8 indep chains ----
        f32x4 acc1[2][2][2];
#pragma unroll
        for (int j = 0; j < 2; ++j)
#pragma unroll
            for (int a = 0; a < 2; ++a)
#pragma unroll
                for (int b = 0; b < 2; ++b) acc1[j][a][b] = vzero;

        __builtin_amdgcn_s_setprio(1);
#pragma unroll
        for (int kb = 0; kb < 4; ++kb) {
            bf16x8 bz[2][2];
#pragma unroll
            for (int j = 0; j < 2; ++j)
#pragma unroll
                for (int mt = 0; mt < 2; ++mt)
                    bz[j][mt] = *(const bf16x8*)(zc_lds[j] + swz128(16*mt + li, kb*32 + 8*g));
#pragma unroll
            for (int j = 0; j < 2; ++j)
#pragma unroll
                for (int ht = 0; ht < 2; ++ht)
#pragma unroll
                    for (int mt = 0; mt < 2; ++mt)
                        acc1[j][ht][mt] = MFMA(w1f[ht][kb], bz[j][mt], acc1[j][ht][mt]);
        }
        __builtin_amdgcn_s_setprio(0);

        // ---- finish L1: tanh(acc + u1) -> h1 ----
#pragma unroll
        for (int j = 0; j < 2; ++j)
#pragma unroll
            for (int ht = 0; ht < 2; ++ht)
#pragma unroll
                for (int mt = 0; mt < 2; ++mt) {
                    float v0 = fast_tanh(acc1[j][ht][mt][0] + uu[j][ht][0]);
                    float v1 = fast_tanh(acc1[j][ht][mt][1] + uu[j][ht][1]);
                    float v2 = fast_tanh(acc1[j][ht][mt][2] + uu[j][ht][2]);
                    float v3 = fast_tanh(acc1[j][ht][mt][3] + uu[j][ht][3]);
                    int m = 16*mt + li;
                    int h = hbase + 16*ht + 4*g;
                    st_pair(h1_lds[j], swz128(m, h),     v0, v1);
                    st_pair(h1_lds[j], swz128(m, h + 2), v2, v3);
                }

        // ---- prefetch next pair's u1 (uu just consumed above) ----
        if (pp < NP) {
#pragma unroll
            for (int j = 0; j < 2; ++j)
#pragma unroll
                for (int ht = 0; ht < 2; ++ht)
                    uu[j][ht] = *(const f32x4*)(u1 + (size_t)(2*pp + j) * 128 + hbase + 16*ht + 4*g);
        }
        __syncthreads();   // B2

        // ---- layer 2 (normal): 32 MFMAs, 8 indep chains ----
        f32x4 acc2[2][2][2];
#pragma unroll
        for (int j = 0; j < 2; ++j)
#pragma unroll
            for (int a = 0; a < 2; ++a)
#pragma unroll
                for (int b = 0; b < 2; ++b) acc2[j][a][b] = vzero;

        __builtin_amdgcn_s_setprio(1);
#pragma unroll
        for (int kb = 0; kb < 4; ++kb) {
            bf16x8 ah[2][2];
#pragma unroll
            for (int j = 0; j < 2; ++j)
#pragma unroll
                for (int mt = 0; mt < 2; ++mt)
                    ah[j][mt] = *(const bf16x8*)(h1_lds[j] + swz128(16*mt + li, kb*32 + 8*g));
#pragma unroll
            for (int j = 0; j < 2; ++j)
#pragma unroll
                for (int mt = 0; mt < 2; ++mt)
#pragma unroll
                    for (int nt = 0; nt < 2; ++nt)
                        acc2[j][mt][nt] = MFMA(ah[j][mt], w2f[nt][kb], acc2[j][mt][nt]);
        }
        __builtin_amdgcn_s_setprio(0);

        // ---- finish L2: tanh, sum over 32 neighbor rows, store ----
#pragma unroll
        for (int j = 0; j < 2; ++j) {
            float s0 = 0.f, s1 = 0.f;
#pragma unroll
            for (int mt = 0; mt < 2; ++mt)
#pragma unroll
                for (int rr = 0; rr < 4; ++rr) {
                    s0 += fast_tanh(acc2[j][mt][0][rr] + b2v[0]);
                    s1 += fast_tanh(acc2[j][mt][1][rr] + b2v[1]);
                }
            s0 += __shfl_xor(s0, 16); s0 += __shfl_xor(s0, 32);
            s1 += __shfl_xor(s1, 16); s1 += __shfl_xor(s1, 32);
            if (lane < 16) {
                bf16* dst = feat + (size_t)(2*p + j) * 256 + 128 + hbase + lane;
                dst[0]  = (bf16)s0;
                dst[16] = (bf16)s1;
            }
        }
        // No bottom barrier: next iter's zc writes sit behind B2, next iter's
        // h1 writes sit behind next B1 — both ordered against this iter's reads.
    }
}

// ---------------------------------------------------------------------------
// Kernel A: cur branch (feat[:,0:128]) + u1 = z @ nw1[:,:128]^T + nb1.
// 64 rows of z per block; both MLP layers operand-swapped; u1 shares the
// staged z tile and the bz fragments of layer 1.
// ---------------------------------------------------------------------------
__global__ __launch_bounds__(256, 2) void cur_kernel(
    const float* __restrict__ z,
    const float* __restrict__ w1, const float* __restrict__ b1,
    const float* __restrict__ w2, const float* __restrict__ b2,
    const float* __restrict__ nw1, const float* __restrict__ nb1,
    bf16* __restrict__ feat, float* __restrict__ u1, int N)
{
    __shared__ char z_lds[64 * 256];
    __shared__ char h1_lds[64 * 256];

    const int t = threadIdx.x;
    const int wv = t >> 6, lane = t & 63, g = lane >> 4, li = lane & 15;
    const int hbase = wv * 32;
    const int n0 = blockIdx.x * 64;

    bf16x8 w1f[2][4], w2f[2][4], wzf[2][4];
#pragma unroll
    for (int ht = 0; ht < 2; ++ht)
#pragma unroll
        for (int kb = 0; kb < 4; ++kb) {
            const float* p1 = w1 + (size_t)(hbase + 16*ht + li) * 128 + kb*32 + 8*g;
            w1f[ht][kb] = cvt8(*(const f32x4*)p1, *(const f32x4*)(p1 + 4));
            const float* p2 = w2 + (size_t)(hbase + 16*ht + li) * 128 + kb*32 + 8*g;
            w2f[ht][kb] = cvt8(*(const f32x4*)p2, *(const f32x4*)(p2 + 4));
            const float* p3 = nw1 + (size_t)(hbase + 16*ht + li) * 256 + kb*32 + 8*g;
            wzf[ht][kb] = cvt8(*(const f32x4*)p3, *(const f32x4*)(p3 + 4));
        }
    float b1v[2][4], b2v[2][4], bnv[2][4];
#pragma unroll
    for (int ht = 0; ht < 2; ++ht)
#pragma unroll
        for (int rr = 0; rr < 4; ++rr) {
            b1v[ht][rr] = b1[hbase + 16*ht + 4*g + rr];
            b2v[ht][rr] = b2[hbase + 16*ht + 4*g + rr];
            bnv[ht][rr] = nb1[hbase + 16*ht + 4*g + rr];
        }

    // stage 64 z rows (clamped for tail block)
    {
        int m = t >> 2;
        int c0 = (t & 3) * 32;
        int row = n0 + m; if (row > N - 1) row = N - 1;
        const float* src = z + (size_t)row * 128 + c0;
#pragma unroll
        for (int q = 0; q < 4; ++q) {
            f32x4 a = *(const f32x4*)(src + 8*q);
            f32x4 b = *(const f32x4*)(src + 8*q + 4);
            *(bf16x8*)(z_lds + swz128(m, c0 + 8*q)) = cvt8(a, b);
        }
    }
    __syncthreads();

    const f32x4 vzero = {0.f, 0.f, 0.f, 0.f};
    f32x4 acc1[2][4], accz[2][4];
#pragma unroll
    for (int a = 0; a < 2; ++a)
#pragma unroll
        for (int b = 0; b < 4; ++b) { acc1[a][b] = vzero; accz[a][b] = vzero; }

#pragma unroll
    for (int kb = 0; kb < 4; ++kb) {
        bf16x8 bz[4];
#pragma unroll
        for (int mt = 0; mt < 4; ++mt)
            bz[mt] = *(const bf16x8*)(z_lds + swz128(16*mt + li, kb*32 + 8*g));
#pragma unroll
        for (int ht = 0; ht < 2; ++ht)
#pragma unroll
            for (int mt = 0; mt < 4; ++mt) {
                acc1[ht][mt] = MFMA(w1f[ht][kb], bz[mt], acc1[ht][mt]);
                accz[ht][mt] = MFMA(wzf[ht][kb], bz[mt], accz[ht][mt]);
            }
    }

    // u1 store (f32): u1[n][h] = accz + nb1
#pragma unroll
    for (int ht = 0; ht < 2; ++ht)
#pragma unroll
        for (int mt = 0; mt < 4; ++mt) {
            int row = n0 + 16*mt + li;
            if (row < N) {
                f32x4 v;
#pragma unroll
                for (int rr = 0; rr < 4; ++rr) v[rr] = accz[ht][mt][rr] + bnv[ht][rr];
                *(f32x4*)(u1 + (size_t)row * 128 + hbase + 16*ht + 4*g) = v;
            }
        }

    // cur L1 finish -> h1
#pragma unroll
    for (int ht = 0; ht < 2; ++ht)
#pragma unroll
        for (int mt = 0; mt < 4; ++mt) {
            float v0 = fast_tanh(acc1[ht][mt][0] + b1v[ht][0]);
            float v1 = fast_tanh(acc1[ht][mt][1] + b1v[ht][1]);
            float v2 = fast_tanh(acc1[ht][mt][2] + b1v[ht][2]);
            float v3 = fast_tanh(acc1[ht][mt][3] + b1v[ht][3]);
            int m = 16*mt + li;
            int h = hbase + 16*ht + 4*g;
            st_pair(h1_lds, swz128(m, h),     v0, v1);
            st_pair(h1_lds, swz128(m, h + 2), v2, v3);
        }
    __syncthreads();

    f32x4 acc2[2][4];
#pragma unroll
    for (int a = 0; a < 2; ++a)
#pragma unroll
        for (int b = 0; b < 4; ++b) acc2[a][b] = vzero;

#pragma unroll
    for (int kb = 0; kb < 4; ++kb) {
        bf16x8 bh[4];
#pragma unroll
        for (int mt = 0; mt < 4; ++mt)
            bh[mt] = *(const bf16x8*)(h1_lds + swz128(16*mt + li, kb*32 + 8*g));
#pragma unroll
        for (int ht = 0; ht < 2; ++ht)
#pragma unroll
            for (int mt = 0; mt < 4; ++mt)
                acc2[ht][mt] = MFMA(w2f[ht][kb], bh[mt], acc2[ht][mt]);
    }
#pragma unroll
    for (int ht = 0; ht < 2; ++ht)
#pragma unroll
        for (int mt = 0; mt < 4; ++mt) {
            float v0 = fast_tanh(acc2[ht][mt][0] + b2v[ht][0]);
            float v1 = fast_tanh(acc2[ht][mt][1] + b2v[ht][1]);
            float v2 = fast_tanh(acc2[ht][mt][2] + b2v[ht][2]);
            float v3 = fast_tanh(acc2[ht][mt][3] + b2v[ht][3]);
            int row = n0 + 16*mt + li;
            if (row < N) {
                int h = hbase + 16*ht + 4*g;
                bf16* dst = feat + (size_t)row * 256 + h;
                bf16x2 p01 = {(bf16)v0, (bf16)v1};
                bf16x2 p23 = {(bf16)v2, (bf16)v3};
                *(bf16x2*)(dst)     = p01;
                *(bf16x2*)(dst + 2) = p23;
            }
        }
}

// ---------------------------------------------------------------------------
// Kernel C: dc = feat[N,256] @ ow^T + ob -> f32 out. 64 rows/block.
// ---------------------------------------------------------------------------
__global__ __launch_bounds__(256, 2) void out_kernel(
    const bf16* __restrict__ feat,
    const float* __restrict__ ow, const float* __restrict__ ob,
    float* __restrict__ out, int N)
{
    __shared__ char f_lds[64 * 512];

    const int t = threadIdx.x, wv = t >> 6, lane = t & 63, g = lane >> 4, li = lane & 15;
    const int cbase = wv * 16;
    const int n0 = blockIdx.x * 64;

    bf16x8 owf[8];
#pragma unroll
    for (int kb = 0; kb < 8; ++kb) {
        const float* p = ow + (size_t)(cbase + li) * 256 + kb*32 + 8*g;
        owf[kb] = cvt8(*(const f32x4*)p, *(const f32x4*)(p + 4));
    }
    float obv = ob[cbase + li];

    {
        int m = t >> 2;
        int c0 = (t & 3) * 64;
        int row = n0 + m; if (row > N - 1) row = N - 1;
        const bf16* src = feat + (size_t)row * 256 + c0;
#pragma unroll
        for (int q = 0; q < 8; ++q)
            *(bf16x8*)(f_lds + swz256(m, c0 + 8*q)) = *(const bf16x8*)(src + 8*q);
    }
    __syncthreads();

    const f32x4 vzero = {0.f, 0.f, 0.f, 0.f};
    f32x4 acc[4];
#pragma unroll
    for (int a = 0; a < 4; ++a) acc[a] = vzero;

#pragma unroll
    for (int kb = 0; kb < 8; ++kb) {
        bf16x8 af[4];
#pragma unroll
        for (int mt = 0; mt < 4; ++mt)
            af[mt] = *(const bf16x8*)(f_lds + swz256(16*mt + li, kb*32 + 8*g));
#pragma unroll
        for (int mt = 0; mt < 4; ++mt)
            acc[mt] = MFMA(af[mt], owf[kb], acc[mt]);
    }
#pragma unroll
    for (int mt = 0; mt < 4; ++mt)
#pragma unroll
        for (int rr = 0; rr < 4; ++rr) {
            int row = n0 + 16*mt + 4*g + rr;
            if (row < N) out[(size_t)row * 64 + cbase + li] = acc[mt][rr] + obv;
        }
}

// ---------------------------------------------------------------------------
extern "C" void kernel_launch(void* const* d_in, const int* in_sizes, int n_in,
                              void* d_out, int out_size, void* d_ws, size_t ws_size,
                              hipStream_t stream) {
    const float* z   = (const float*)d_in[0];
    const float* zn  = (const float*)d_in[1];
    const float* cw1 = (const float*)d_in[2];
    const float* cb1 = (const float*)d_in[3];
    const float* cw2 = (const float*)d_in[4];
    const float* cb2 = (const float*)d_in[5];
    const float* nw1 = (const float*)d_in[6];
    const float* nb1 = (const float*)d_in[7];
    const float* nw2 = (const float*)d_in[8];
    const float* nb2 = (const float*)d_in[9];
    const float* ow  = (const float*)d_in[10];
    const float* ob  = (const float*)d_in[11];
    float* out = (float*)d_out;

    const int N  = in_sizes[0] / 128;          // 20000
    const int NP = N / 2;                      // pairs for nbr_kernel
    const int nblk = (N + 63) / 64;            // 313

    bf16*  feat = (bf16*)d_ws;                            // [N][256] bf16
    float* u1   = (float*)((char*)d_ws + (size_t)N * 256 * sizeof(bf16)); // [N][128] f32

    (void)n_in; (void)out_size; (void)ws_size;

    cur_kernel<<<nblk, 256, 0, stream>>>(z, cw1, cb1, cw2, cb2, nw1, nb1, feat, u1, N);
    nbr_kernel<<<512, 256, 0, stream>>>(zn, u1, nw1, nw2, nb2, feat, NP);
    out_kernel<<<nblk, 256, 0, stream>>>(feat, ow, ob, out, N);
}

// Round 3
// 125.868 us; speedup vs baseline: 1.0840x; 1.0034x over previous
//
#include <hip/hip_runtime.h>

// ---------------------------------------------------------------------------
// MLP-GNN fused op for MI355X (gfx950).
//   v  = tanh(tanh(z @ cw1^T + cb1) @ cw2^T + cb2)                    [N,128]
//   vn = tanh(tanh([z|z_] @ nw1^T + nb1) @ nw2^T + nb2).sum(axis=K)   [N,128]
//   dc = [v | vn] @ ow^T + ob                                         [N,64]
// bf16 MFMA (16x16x32), f32 accum. 3 kernels:
//   cur_kernel:  v -> feat[:,0:128]  AND  u1[n][h] = z@nw1[:,:128]^T + nb1
//   nbr_kernel:  vn -> feat[:,128:256]; 2 n's per iteration.
//                KEY (R2): raw s_barrier (no vmcnt drain) so prefetched HBM
//                loads stay in flight across both loop barriers.
//   out_kernel:  dc -> d_out (f32)
// ---------------------------------------------------------------------------

typedef __bf16 bf16;
typedef __bf16 bf16x2 __attribute__((ext_vector_type(2)));
typedef __bf16 bf16x8 __attribute__((ext_vector_type(8)));
typedef float  f32x4  __attribute__((ext_vector_type(4)));

#define MFMA(a, b, c) __builtin_amdgcn_mfma_f32_16x16x32_bf16((a), (b), (c), 0, 0, 0)

// Workgroup barrier WITHOUT the vmcnt(0) drain __syncthreads() implies.
// lgkmcnt(0) makes this wave's LDS writes visible before the barrier; global
// loads issued before this stay in flight across it (HK/m201 pattern).
__device__ __forceinline__ void block_sync_lds() {
    asm volatile("s_waitcnt lgkmcnt(0)\n\ts_barrier" ::: "memory");
}

// tanh(x) = sign(x) * (1 - 2/(e^{2|x|}+1)); exp2-based, inf-safe (inf -> 1).
__device__ __forceinline__ float fast_tanh(float x) {
    float ax = __builtin_fabsf(x);
    float t  = __builtin_amdgcn_exp2f(ax * 2.885390081777927f); // 2*log2(e)
    float r  = 1.0f - 2.0f * __builtin_amdgcn_rcpf(t + 1.0f);
    return __builtin_copysignf(r, x);
}

__device__ __forceinline__ bf16x8 cvt8(f32x4 a, f32x4 b) {
    bf16x8 r;
    r[0] = (bf16)a[0]; r[1] = (bf16)a[1]; r[2] = (bf16)a[2]; r[3] = (bf16)a[3];
    r[4] = (bf16)b[0]; r[5] = (bf16)b[1]; r[6] = (bf16)b[2]; r[7] = (bf16)b[3];
    return r;
}

// LDS tiles with 128-bf16 rows (256 B = 16 x 16B chunks), chunk-XOR swizzle so
// ds_read_b128 frag reads (16 rows x same chunk) are bank-spread.
__device__ __forceinline__ int swz128(int row, int col) {
    int c = (col >> 3) ^ (row & 15);
    return row * 256 + c * 16 + (col & 7) * 2;
}
// 256-bf16 rows (512 B = 32 chunks)
__device__ __forceinline__ int swz256(int row, int col) {
    int c = (col >> 3) ^ (row & 15);
    return row * 512 + c * 16 + (col & 7) * 2;
}

__device__ __forceinline__ void st_pair(char* base, int off, float a, float b) {
    bf16x2 p = {(bf16)a, (bf16)b};
    *(bf16x2*)(base + off) = p;
}

// ---------------------------------------------------------------------------
// Kernel B: neighbor branch. One PAIR (2p, 2p+1) per iteration; 32 rows of z_
// each. L1 operand-swapped over the z_-half only; the z-half arrives as the
// precomputed per-row bias u1[n][h]. 2 raw barriers per pair; z_ prefetch
// issued after B1, u1 prefetch after its consumption — both stay in flight
// across barriers and are waited with counted vmcnt at the consumption point.
// ---------------------------------------------------------------------------
__global__ __launch_bounds__(256, 2) void nbr_kernel(
    const float* __restrict__ zn, const float* __restrict__ u1,
    const float* __restrict__ w1, const float* __restrict__ w2,
    const float* __restrict__ b2,
    bf16* __restrict__ feat, int NP)
{
    __shared__ char zc_lds[2][32 * 256];
    __shared__ char h1_lds[2][32 * 256];

    const int t = threadIdx.x;
    const int wv = t >> 6, lane = t & 63, g = lane >> 4, li = lane & 15;
    const int hbase = wv * 32;

    // z_-half of W1 (cols 128..255) as swapped-L1 A-frags
    bf16x8 w1f[2][4];
#pragma unroll
    for (int ht = 0; ht < 2; ++ht)
#pragma unroll
        for (int kb = 0; kb < 4; ++kb) {
            const float* p = w1 + (size_t)(hbase + 16*ht + li) * 256 + 128 + kb*32 + 8*g;
            w1f[ht][kb] = cvt8(*(const f32x4*)p, *(const f32x4*)(p + 4));
        }
    bf16x8 w2f[2][4];
#pragma unroll
    for (int nt = 0; nt < 2; ++nt)
#pragma unroll
        for (int kb = 0; kb < 4; ++kb) {
            const float* p = w2 + (size_t)(hbase + 16*nt + li) * 128 + kb*32 + 8*g;
            w2f[nt][kb] = cvt8(*(const f32x4*)p, *(const f32x4*)(p + 4));
        }
    float b2v[2];
#pragma unroll
    for (int nt = 0; nt < 2; ++nt) b2v[nt] = b2[hbase + 16*nt + li];

    const int sm  = t >> 3;        // staging row 0..31
    const int scf = (t & 7) * 16;  // staging col (floats)
    const int stride = gridDim.x;

    f32x4 r[2][4];   // staged z_ rows for the pair
    f32x4 uu[2][2];  // u1 bias for the pair
    {
        int p = blockIdx.x;
#pragma unroll
        for (int j = 0; j < 2; ++j) {
            const float* src = zn + ((size_t)(2*p + j) * 32 + sm) * 128 + scf;
#pragma unroll
            for (int q = 0; q < 4; ++q) r[j][q] = *(const f32x4*)(src + 4*q);
#pragma unroll
            for (int ht = 0; ht < 2; ++ht)
                uu[j][ht] = *(const f32x4*)(u1 + (size_t)(2*p + j) * 128 + hbase + 16*ht + 4*g);
        }
    }

    const f32x4 vzero = {0.f, 0.f, 0.f, 0.f};

    for (int p = blockIdx.x; p < NP; p += stride) {
        // ---- write staged pair into LDS (counted vmcnt wait on r here) ----
#pragma unroll
        for (int j = 0; j < 2; ++j) {
            *(bf16x8*)(zc_lds[j] + swz128(sm, scf))     = cvt8(r[j][0], r[j][1]);
            *(bf16x8*)(zc_lds[j] + swz128(sm, scf + 8)) = cvt8(r[j][2], r[j][3]);
        }
        block_sync_lds();   // B1 (no vmcnt drain)

        // ---- issue next pair's z_ loads; they ride across B2/B1 ----
        const int pp = p + stride;
        if (pp < NP) {
#pragma unroll
            for (int j = 0; j < 2; ++j) {
                const float* src = zn + ((size_t)(2*pp + j) * 32 + sm) * 128 + scf;
#pragma unroll
                for (int q = 0; q < 4; ++q) r[j][q] = *(const f32x4*)(src + 4*q);
            }
        }

        // ---- layer 1 (swapped, z_-half only): 32 MFMAs, 8 indep chains ----
        f32x4 acc1[2][2][2];
#pragma unroll
        for (int j = 0; j < 2; ++j)
#pragma unroll
            for (int a = 0; a < 2; ++a)
#pragma unroll
                for (int b = 0; b < 2; ++b) acc1[j][a][b] = vzero;

        __builtin_amdgcn_s_setprio(1);
#pragma unroll
        for (int kb = 0; kb < 4; ++kb) {
            bf16x8 bz[2][2];
#pragma unroll
            for (int j = 0; j < 2; ++j)
#pragma unroll
                for (int mt = 0; mt < 2; ++mt)
                    bz[j][mt] = *(const bf16x8*)(zc_lds[j] + swz128(16*mt + li, kb*32 + 8*g));
#pragma unroll
            for (int j = 0; j < 2; ++j)
#pragma unroll
                for (int ht = 0; ht < 2; ++ht)
#pragma unroll
                    for (int mt = 0; mt < 2; ++mt)
                        acc1[j][ht][mt] = MFMA(w1f[ht][kb], bz[j][mt], acc1[j][ht][mt]);
        }
        __builtin_amdgcn_s_setprio(0);

        // ---- finish L1: tanh(acc + u1) -> h1 (counted vmcnt wait on uu) ----
#pragma unroll
        for (int j = 0; j < 2; ++j)
#pragma unroll
            for (int ht = 0; ht < 2; ++ht)
#pragma unroll
                for (int mt = 0; mt < 2; ++mt) {
                    float v0 = fast_tanh(acc1[j][ht][mt][0] + uu[j][ht][0]);
                    float v1 = fast_tanh(acc1[j][ht][mt][1] + uu[j][ht][1]);
                    float v2 = fast_tanh(acc1[j][ht][mt][2] + uu[j][ht][2]);
                    float v3 = fast_tanh(acc1[j][ht][mt][3] + uu[j][ht][3]);
                    int m = 16*mt + li;
                    int h = hbase + 16*ht + 4*g;
                    st_pair(h1_lds[j], swz128(m, h),     v0, v1);
                    st_pair(h1_lds[j], swz128(m, h + 2), v2, v3);
                }

        // ---- issue next pair's u1 loads (uu just consumed above) ----
        if (pp < NP) {
#pragma unroll
            for (int j = 0; j < 2; ++j)
#pragma unroll
                for (int ht = 0; ht < 2; ++ht)
                    uu[j][ht] = *(const f32x4*)(u1 + (size_t)(2*pp + j) * 128 + hbase + 16*ht + 4*g);
        }
        block_sync_lds();   // B2 (no vmcnt drain — prefetches stay in flight)

        // ---- layer 2 (normal): 32 MFMAs, 8 indep chains ----
        f32x4 acc2[2][2][2];
#pragma unroll
        for (int j = 0; j < 2; ++j)
#pragma unroll
            for (int a = 0; a < 2; ++a)
#pragma unroll
                for (int b = 0; b < 2; ++b) acc2[j][a][b] = vzero;

        __builtin_amdgcn_s_setprio(1);
#pragma unroll
        for (int kb = 0; kb < 4; ++kb) {
            bf16x8 ah[2][2];
#pragma unroll
            for (int j = 0; j < 2; ++j)
#pragma unroll
                for (int mt = 0; mt < 2; ++mt)
                    ah[j][mt] = *(const bf16x8*)(h1_lds[j] + swz128(16*mt + li, kb*32 + 8*g));
#pragma unroll
            for (int j = 0; j < 2; ++j)
#pragma unroll
                for (int mt = 0; mt < 2; ++mt)
#pragma unroll
                    for (int nt = 0; nt < 2; ++nt)
                        acc2[j][mt][nt] = MFMA(ah[j][mt], w2f[nt][kb], acc2[j][mt][nt]);
        }
        __builtin_amdgcn_s_setprio(0);

        // ---- finish L2: tanh, sum over 32 neighbor rows, store ----
#pragma unroll
        for (int j = 0; j < 2; ++j) {
            float s0 = 0.f, s1 = 0.f;
#pragma unroll
            for (int mt = 0; mt < 2; ++mt)
#pragma unroll
                for (int rr = 0; rr < 4; ++rr) {
                    s0 += fast_tanh(acc2[j][mt][0][rr] + b2v[0]);
                    s1 += fast_tanh(acc2[j][mt][1][rr] + b2v[1]);
                }
            s0 += __shfl_xor(s0, 16); s0 += __shfl_xor(s0, 32);
            s1 += __shfl_xor(s1, 16); s1 += __shfl_xor(s1, 32);
            if (lane < 16) {
                bf16* dst = feat + (size_t)(2*p + j) * 256 + 128 + hbase + lane;
                dst[0]  = (bf16)s0;
                dst[16] = (bf16)s1;
            }
        }
        // No bottom barrier: next iter's zc writes sit behind B2(i) (all zc
        // reads happened before it); next iter's h1 writes sit behind B1(i+1)
        // (all h1 reads retired before each wave reaches B1(i+1)).
    }
}

// ---------------------------------------------------------------------------
// Kernel A: cur branch (feat[:,0:128]) + u1 = z @ nw1[:,:128]^T + nb1.
// ---------------------------------------------------------------------------
__global__ __launch_bounds__(256, 2) void cur_kernel(
    const float* __restrict__ z,
    const float* __restrict__ w1, const float* __restrict__ b1,
    const float* __restrict__ w2, const float* __restrict__ b2,
    const float* __restrict__ nw1, const float* __restrict__ nb1,
    bf16* __restrict__ feat, float* __restrict__ u1, int N)
{
    __shared__ char z_lds[64 * 256];
    __shared__ char h1_lds[64 * 256];

    const int t = threadIdx.x;
    const int wv = t >> 6, lane = t & 63, g = lane >> 4, li = lane & 15;
    const int hbase = wv * 32;
    const int n0 = blockIdx.x * 64;

    bf16x8 w1f[2][4], w2f[2][4], wzf[2][4];
#pragma unroll
    for (int ht = 0; ht < 2; ++ht)
#pragma unroll
        for (int kb = 0; kb < 4; ++kb) {
            const float* p1 = w1 + (size_t)(hbase + 16*ht + li) * 128 + kb*32 + 8*g;
            w1f[ht][kb] = cvt8(*(const f32x4*)p1, *(const f32x4*)(p1 + 4));
            const float* p2 = w2 + (size_t)(hbase + 16*ht + li) * 128 + kb*32 + 8*g;
            w2f[ht][kb] = cvt8(*(const f32x4*)p2, *(const f32x4*)(p2 + 4));
            const float* p3 = nw1 + (size_t)(hbase + 16*ht + li) * 256 + kb*32 + 8*g;
            wzf[ht][kb] = cvt8(*(const f32x4*)p3, *(const f32x4*)(p3 + 4));
        }
    float b1v[2][4], b2v[2][4], bnv[2][4];
#pragma unroll
    for (int ht = 0; ht < 2; ++ht)
#pragma unroll
        for (int rr = 0; rr < 4; ++rr) {
            b1v[ht][rr] = b1[hbase + 16*ht + 4*g + rr];
            b2v[ht][rr] = b2[hbase + 16*ht + 4*g + rr];
            bnv[ht][rr] = nb1[hbase + 16*ht + 4*g + rr];
        }

    // stage 64 z rows (clamped for tail block)
    {
        int m = t >> 2;
        int c0 = (t & 3) * 32;
        int row = n0 + m; if (row > N - 1) row = N - 1;
        const float* src = z + (size_t)row * 128 + c0;
#pragma unroll
        for (int q = 0; q < 4; ++q) {
            f32x4 a = *(const f32x4*)(src + 8*q);
            f32x4 b = *(const f32x4*)(src + 8*q + 4);
            *(bf16x8*)(z_lds + swz128(m, c0 + 8*q)) = cvt8(a, b);
        }
    }
    __syncthreads();

    const f32x4 vzero = {0.f, 0.f, 0.f, 0.f};
    f32x4 acc1[2][4], accz[2][4];
#pragma unroll
    for (int a = 0; a < 2; ++a)
#pragma unroll
        for (int b = 0; b < 4; ++b) { acc1[a][b] = vzero; accz[a][b] = vzero; }

#pragma unroll
    for (int kb = 0; kb < 4; ++kb) {
        bf16x8 bz[4];
#pragma unroll
        for (int mt = 0; mt < 4; ++mt)
            bz[mt] = *(const bf16x8*)(z_lds + swz128(16*mt + li, kb*32 + 8*g));
#pragma unroll
        for (int ht = 0; ht < 2; ++ht)
#pragma unroll
            for (int mt = 0; mt < 4; ++mt) {
                acc1[ht][mt] = MFMA(w1f[ht][kb], bz[mt], acc1[ht][mt]);
                accz[ht][mt] = MFMA(wzf[ht][kb], bz[mt], accz[ht][mt]);
            }
    }

    // u1 store (f32)
#pragma unroll
    for (int ht = 0; ht < 2; ++ht)
#pragma unroll
        for (int mt = 0; mt < 4; ++mt) {
            int row = n0 + 16*mt + li;
            if (row < N) {
                f32x4 v;
#pragma unroll
                for (int rr = 0; rr < 4; ++rr) v[rr] = accz[ht][mt][rr] + bnv[ht][rr];
                *(f32x4*)(u1 + (size_t)row * 128 + hbase + 16*ht + 4*g) = v;
            }
        }

    // cur L1 finish -> h1
#pragma unroll
    for (int ht = 0; ht < 2; ++ht)
#pragma unroll
        for (int mt = 0; mt < 4; ++mt) {
            float v0 = fast_tanh(acc1[ht][mt][0] + b1v[ht][0]);
            float v1 = fast_tanh(acc1[ht][mt][1] + b1v[ht][1]);
            float v2 = fast_tanh(acc1[ht][mt][2] + b1v[ht][2]);
            float v3 = fast_tanh(acc1[ht][mt][3] + b1v[ht][3]);
            int m = 16*mt + li;
            int h = hbase + 16*ht + 4*g;
            st_pair(h1_lds, swz128(m, h),     v0, v1);
            st_pair(h1_lds, swz128(m, h + 2), v2, v3);
        }
    __syncthreads();

    f32x4 acc2[2][4];
#pragma unroll
    for (int a = 0; a < 2; ++a)
#pragma unroll
        for (int b = 0; b < 4; ++b) acc2[a][b] = vzero;

#pragma unroll
    for (int kb = 0; kb < 4; ++kb) {
        bf16x8 bh[4];
#pragma unroll
        for (int mt = 0; mt < 4; ++mt)
            bh[mt] = *(const bf16x8*)(h1_lds + swz128(16*mt + li, kb*32 + 8*g));
#pragma unroll
        for (int ht = 0; ht < 2; ++ht)
#pragma unroll
            for (int mt = 0; mt < 4; ++mt)
                acc2[ht][mt] = MFMA(w2f[ht][kb], bh[mt], acc2[ht][mt]);
    }
#pragma unroll
    for (int ht = 0; ht < 2; ++ht)
#pragma unroll
        for (int mt = 0; mt < 4; ++mt) {
            float v0 = fast_tanh(acc2[ht][mt][0] + b2v[ht][0]);
            float v1 = fast_tanh(acc2[ht][mt][1] + b2v[ht][1]);
            float v2 = fast_tanh(acc2[ht][mt][2] + b2v[ht][2]);
            float v3 = fast_tanh(acc2[ht][mt][3] + b2v[ht][3]);
            int row = n0 + 16*mt + li;
            if (row < N) {
                int h = hbase + 16*ht + 4*g;
                bf16* dst = feat + (size_t)row * 256 + h;
                bf16x2 p01 = {(bf16)v0, (bf16)v1};
                bf16x2 p23 = {(bf16)v2, (bf16)v3};
                *(bf16x2*)(dst)     = p01;
                *(bf16x2*)(dst + 2) = p23;
            }
        }
}

// ---------------------------------------------------------------------------
// Kernel C: dc = feat[N,256] @ ow^T + ob -> f32 out. 64 rows/block.
// ---------------------------------------------------------------------------
__global__ __launch_bounds__(256, 2) void out_kernel(
    const bf16* __restrict__ feat,
    const float* __restrict__ ow, const float* __restrict__ ob,
    float* __restrict__ out, int N)
{
    __shared__ char f_lds[64 * 512];

    const int t = threadIdx.x, wv = t >> 6, lane = t & 63, g = lane >> 4, li = lane & 15;
    const int cbase = wv * 16;
    const int n0 = blockIdx.x * 64;

    bf16x8 owf[8];
#pragma unroll
    for (int kb = 0; kb < 8; ++kb) {
        const float* p = ow + (size_t)(cbase + li) * 256 + kb*32 + 8*g;
        owf[kb] = cvt8(*(const f32x4*)p, *(const f32x4*)(p + 4));
    }
    float obv = ob[cbase + li];

    {
        int m = t >> 2;
        int c0 = (t & 3) * 64;
        int row = n0 + m; if (row > N - 1) row = N - 1;
        const bf16* src = feat + (size_t)row * 256 + c0;
#pragma unroll
        for (int q = 0; q < 8; ++q)
            *(bf16x8*)(f_lds + swz256(m, c0 + 8*q)) = *(const bf16x8*)(src + 8*q);
    }
    __syncthreads();

    const f32x4 vzero = {0.f, 0.f, 0.f, 0.f};
    f32x4 acc[4];
#pragma unroll
    for (int a = 0; a < 4; ++a) acc[a] = vzero;

#pragma unroll
    for (int kb = 0; kb < 8; ++kb) {
        bf16x8 af[4];
#pragma unroll
        for (int mt = 0; mt < 4; ++mt)
            af[mt] = *(const bf16x8*)(f_lds + swz256(16*mt + li, kb*32 + 8*g));
#pragma unroll
        for (int mt = 0; mt < 4; ++mt)
            acc[mt] = MFMA(af[mt], owf[kb], acc[mt]);
    }
#pragma unroll
    for (int mt = 0; mt < 4; ++mt)
#pragma unroll
        for (int rr = 0; rr < 4; ++rr) {
            int row = n0 + 16*mt + 4*g + rr;
            if (row < N) out[(size_t)row * 64 + cbase + li] = acc[mt][rr] + obv;
        }
}

// ---------------------------------------------------------------------------
extern "C" void kernel_launch(void* const* d_in, const int* in_sizes, int n_in,
                              void* d_out, int out_size, void* d_ws, size_t ws_size,
                              hipStream_t stream) {
    const float* z   = (const float*)d_in[0];
    const float* zn  = (const float*)d_in[1];
    const float* cw1 = (const float*)d_in[2];
    const float* cb1 = (const float*)d_in[3];
    const float* cw2 = (const float*)d_in[4];
    const float* cb2 = (const float*)d_in[5];
    const float* nw1 = (const float*)d_in[6];
    const float* nb1 = (const float*)d_in[7];
    const float* nw2 = (const float*)d_in[8];
    const float* nb2 = (const float*)d_in[9];
    const float* ow  = (const float*)d_in[10];
    const float* ob  = (const float*)d_in[11];
    float* out = (float*)d_out;

    const int N  = in_sizes[0] / 128;          // 20000
    const int NP = N / 2;                      // pairs for nbr_kernel
    const int nblk = (N + 63) / 64;            // 313

    bf16*  feat = (bf16*)d_ws;                            // [N][256] bf16
    float* u1   = (float*)((char*)d_ws + (size_t)N * 256 * sizeof(bf16)); // [N][128] f32

    (void)n_in; (void)out_size; (void)ws_size;

    cur_kernel<<<nblk, 256, 0, stream>>>(z, cw1, cb1, cw2, cb2, nw1, nb1, feat, u1, N);
    nbr_kernel<<<512, 256, 0, stream>>>(zn, u1, nw1, nw2, nb2, feat, NP);
    out_kernel<<<nblk, 256, 0, stream>>>(feat, ow, ob, out, N);
}